// Round 1
// baseline (169.849 us; speedup 1.0000x reference)
//
#include <hip/hip_runtime.h>
#include <math.h>

#ifndef __has_builtin
#define __has_builtin(x) 0
#endif
#if __has_builtin(__builtin_amdgcn_exp2f)
#define EXP2F(x) __builtin_amdgcn_exp2f(x)
#else
#define EXP2F(x) exp2f(x)
#endif

constexpr int KBINS = 32;
constexpr int MM_BLOCKS = 512;        // minmax stage-1 blocks
constexpr int MAIN_BLOCKS = 1024;     // main histogram blocks (4 waves each)
constexpr int WAVES_PER_BLOCK = 4;
constexpr int BATCH = 32;             // samples per wave-batch
constexpr int RED_BLOCKS = 64;        // stage-A reduction blocks (16 partials each)
constexpr int PART_OFF_F = 4096;      // float offset of pab partials in ws
constexpr size_t REDA_OFF_B = (size_t)(PART_OFF_F + MAIN_BLOCKS * KBINS * KBINS) * 4;

// ---------------- Stage 0: global min/max over both arrays ----------------
__global__ __launch_bounds__(256) void k_minmax(const float* __restrict__ p,
                                                const float* __restrict__ t,
                                                int n, float* __restrict__ ws) {
  int tid = blockIdx.x * 256 + threadIdx.x;
  int nth = gridDim.x * 256;
  float mn = INFINITY, mx = -INFINITY;
  int n4 = n >> 2;
  const float4* p4 = (const float4*)p;
  const float4* t4 = (const float4*)t;
  for (int i = tid; i < n4; i += nth) {
    float4 a = p4[i];
    mn = fminf(mn, fminf(fminf(a.x, a.y), fminf(a.z, a.w)));
    mx = fmaxf(mx, fmaxf(fmaxf(a.x, a.y), fmaxf(a.z, a.w)));
    float4 b = t4[i];
    mn = fminf(mn, fminf(fminf(b.x, b.y), fminf(b.z, b.w)));
    mx = fmaxf(mx, fmaxf(fmaxf(b.x, b.y), fmaxf(b.z, b.w)));
  }
  for (int i = (n4 << 2) + tid; i < n; i += nth) {
    mn = fminf(mn, fminf(p[i], t[i]));
    mx = fmaxf(mx, fmaxf(p[i], t[i]));
  }
  for (int off = 32; off; off >>= 1) {
    mn = fminf(mn, __shfl_xor(mn, off, 64));
    mx = fmaxf(mx, __shfl_xor(mx, off, 64));
  }
  __shared__ float smn[4], smx[4];
  int wv = threadIdx.x >> 6;
  if ((threadIdx.x & 63) == 0) { smn[wv] = mn; smx[wv] = mx; }
  __syncthreads();
  if (threadIdx.x == 0) {
    mn = fminf(fminf(smn[0], smn[1]), fminf(smn[2], smn[3]));
    mx = fmaxf(fmaxf(smx[0], smx[1]), fmaxf(smx[2], smx[3]));
    ws[16 + 2 * blockIdx.x] = mn;
    ws[17 + 2 * blockIdx.x] = mx;
  }
}

// ---------------- Stage 1: Parzen weights + 32x32 joint histogram ----------------
// Each wave owns a private 32x32 fp32 accumulator: lane (i=lane>>3, j=lane&7)
// holds the 4x4 tile rows [4i,4i+4) x cols [4j,4j+4).
__global__ __launch_bounds__(256) void k_main(const float* __restrict__ p,
                                              const float* __restrict__ t,
                                              int n, float* __restrict__ ws) {
  __shared__ float lds[WAVES_PER_BLOCK][2][BATCH][KBINS];  // 32 KB
  __shared__ float s_par[4];

  const int tidx = threadIdx.x;
  const int lane = tidx & 63;
  const int wv = tidx >> 6;

  // per-block parameter computation from minmax partials (wave 0 only)
  if (tidx < 64) {
    float mn = INFINITY, mx = -INFINITY;
    for (int b = lane; b < MM_BLOCKS; b += 64) {
      mn = fminf(mn, ws[16 + 2 * b]);
      mx = fmaxf(mx, ws[17 + 2 * b]);
    }
    for (int off = 32; off; off >>= 1) {
      mn = fminf(mn, __shfl_xor(mn, off, 64));
      mx = fmaxf(mx, __shfl_xor(mx, off, 64));
    }
    if (lane == 0) {
      bool in_range = (mx <= 1.0f) && (mn >= 0.0f);
      float minv = in_range ? 0.0f : mn;
      float maxv = in_range ? 1.0f : mx;
      float drange = maxv - minv;
      float sigma = drange * (1.0f / (KBINS - 1));          // SIGMA_RATIO = 1
      float preterm = 1.0f / (2.0f * sigma * sigma);
      s_par[0] = minv;
      s_par[1] = drange * (1.0f / (KBINS - 1));             // bin spacing
      s_par[2] = preterm * 1.44269504088896340736f;         // preterm * log2(e)
    }
  }
  __syncthreads();
  const float minv = s_par[0], delta = s_par[1];
  const float npl2 = -s_par[2];

  const int q = lane & 7;    // bin-quad in weight phase == col-quad j in accumulate
  const int sg = lane >> 3;  // sample subgroup in weight phase == row-quad i

  // per-lane bin centers (4 bins of quad q)
  float cc[4];
#pragma unroll
  for (int r = 0; r < 4; ++r) cc[r] = minv + delta * (float)(4 * q + r);

  float acc[4][4] = {{0.0f, 0.0f, 0.0f, 0.0f},
                     {0.0f, 0.0f, 0.0f, 0.0f},
                     {0.0f, 0.0f, 0.0f, 0.0f},
                     {0.0f, 0.0f, 0.0f, 0.0f}};

  const int nwaves = MAIN_BLOCKS * WAVES_PER_BLOCK;  // 4096
  const int per_wave = n / nwaves;                   // 512 for n = 2^21
  const long long base = ((long long)blockIdx.x * WAVES_PER_BLOCK + wv) * per_wave;

  float* wa = &lds[wv][0][0][0];
  float* wb = &lds[wv][1][0][0];
  const int li = lane & 31;
  const float* __restrict__ src = (lane & 32) ? t : p;

  for (int it = 0; it < per_wave; it += BATCH) {
    const long long b0 = base + it;
    // lanes 0-31 hold p[b0+0..31], lanes 32-63 hold t[b0+0..31]
    float xload = src[b0 + li];

#pragma unroll
    for (int h = 0; h < BATCH / 8; ++h) {
      int s = h * 8 + sg;
      {  // wa (pred)
        float x = __shfl(xload, s, 64);
        float d0 = x - cc[0], d1 = x - cc[1], d2 = x - cc[2], d3 = x - cc[3];
        float e0 = EXP2F(npl2 * d0 * d0);
        float e1 = EXP2F(npl2 * d1 * d1);
        float e2 = EXP2F(npl2 * d2 * d2);
        float e3 = EXP2F(npl2 * d3 * d3);
        float rs = (e0 + e1) + (e2 + e3);
        rs += __shfl_xor(rs, 1, 64);
        rs += __shfl_xor(rs, 2, 64);
        rs += __shfl_xor(rs, 4, 64);
        float inv = 1.0f / rs;
        *(float4*)(wa + s * KBINS + 4 * q) =
            make_float4(e0 * inv, e1 * inv, e2 * inv, e3 * inv);
      }
      {  // wb (target)
        float x = __shfl(xload, 32 + s, 64);
        float d0 = x - cc[0], d1 = x - cc[1], d2 = x - cc[2], d3 = x - cc[3];
        float e0 = EXP2F(npl2 * d0 * d0);
        float e1 = EXP2F(npl2 * d1 * d1);
        float e2 = EXP2F(npl2 * d2 * d2);
        float e3 = EXP2F(npl2 * d3 * d3);
        float rs = (e0 + e1) + (e2 + e3);
        rs += __shfl_xor(rs, 1, 64);
        rs += __shfl_xor(rs, 2, 64);
        rs += __shfl_xor(rs, 4, 64);
        float inv = 1.0f / rs;
        *(float4*)(wb + s * KBINS + 4 * q) =
            make_float4(e0 * inv, e1 * inv, e2 * inv, e3 * inv);
      }
    }
    __syncthreads();  // make weights visible (cross-lane LDS)

#pragma unroll 4
    for (int s = 0; s < BATCH; ++s) {
      const float4 a4 = *(const float4*)(wa + s * KBINS + 4 * sg);
      const float4 b4 = *(const float4*)(wb + s * KBINS + 4 * q);
      const float ar[4] = {a4.x, a4.y, a4.z, a4.w};
      const float br[4] = {b4.x, b4.y, b4.z, b4.w};
#pragma unroll
      for (int r = 0; r < 4; ++r)
#pragma unroll
        for (int c = 0; c < 4; ++c) acc[r][c] = fmaf(ar[r], br[c], acc[r][c]);
    }
    __syncthreads();  // protect LDS reuse in next batch
  }

  // block-level reduction of the 4 per-wave 32x32 accumulators
  float* red = &lds[0][0][0][0];  // reuse; per-wave region is 2048 floats
#pragma unroll
  for (int r = 0; r < 4; ++r)
#pragma unroll
    for (int c = 0; c < 4; ++c)
      red[wv * 2048 + (4 * sg + r) * KBINS + (4 * q + c)] = acc[r][c];
  __syncthreads();

  int cell = tidx * 4;
  float4 out4;
  out4.x = ((red[cell + 0] + red[2048 + cell + 0]) +
            (red[4096 + cell + 0] + red[6144 + cell + 0]));
  out4.y = ((red[cell + 1] + red[2048 + cell + 1]) +
            (red[4096 + cell + 1] + red[6144 + cell + 1]));
  out4.z = ((red[cell + 2] + red[2048 + cell + 2]) +
            (red[4096 + cell + 2] + red[6144 + cell + 2]));
  out4.w = ((red[cell + 3] + red[2048 + cell + 3]) +
            (red[4096 + cell + 3] + red[6144 + cell + 3]));
  float4* part = (float4*)(ws + PART_OFF_F + (size_t)blockIdx.x * 1024);
  part[tidx] = out4;
}

// ---------------- Stage 2a: reduce 1024 fp32 partials -> 64 fp64 partials ----------------
__global__ __launch_bounds__(1024) void k_reduceA(float* __restrict__ ws) {
  const float* part = ws + PART_OFF_F;
  double* outp = (double*)((char*)ws + REDA_OFF_B);
  int tid = threadIdx.x;
  int r = blockIdx.x;
  double s = 0.0;
#pragma unroll
  for (int b = 0; b < MAIN_BLOCKS / RED_BLOCKS; ++b)
    s += (double)part[(size_t)(r * (MAIN_BLOCKS / RED_BLOCKS) + b) * 1024 + tid];
  outp[(size_t)r * 1024 + tid] = s;
}

// ---------------- Stage 2b: final fp64 reduce + MI formula ----------------
__global__ __launch_bounds__(1024) void k_final(const float* __restrict__ ws_f,
                                                float* __restrict__ out, int n) {
  const double* parts = (const double*)((const char*)ws_f + REDA_OFF_B);
  __shared__ double pab_s[1024];
  __shared__ double pa_s[32], pb_s[32];
  __shared__ double wsum[16];
  int tid = threadIdx.x;
  double s = 0.0;
#pragma unroll 8
  for (int r = 0; r < RED_BLOCKS; ++r) s += parts[(size_t)r * 1024 + tid];
  double pab = s / (double)n;
  pab_s[tid] = pab;
  __syncthreads();
  if (tid < 32) {
    double a = 0.0;
    for (int l = 0; l < 32; ++l) a += pab_s[tid * 32 + l];
    pa_s[tid] = a;
  } else if (tid < 64) {
    int l = tid - 32;
    double b = 0.0;
    for (int k2 = 0; k2 < 32; ++k2) b += pab_s[k2 * 32 + l];
    pb_s[l] = b;
  }
  __syncthreads();
  int k = tid >> 5, l = tid & 31;
  double papb = pa_s[k] * pb_s[l];
  double v = pab * log((pab + 1e-7) / (papb + 1e-7) + 1e-7);
  for (int off = 32; off; off >>= 1) v += __shfl_down(v, off, 64);
  if ((tid & 63) == 0) wsum[tid >> 6] = v;
  __syncthreads();
  if (tid < 64) {
    double w = (tid < 16) ? wsum[tid] : 0.0;
    for (int off = 8; off; off >>= 1) w += __shfl_down(w, off, 64);
    if (tid == 0) out[0] = (float)(-w);
  }
}

extern "C" void kernel_launch(void* const* d_in, const int* in_sizes, int n_in,
                              void* d_out, int out_size, void* d_ws, size_t ws_size,
                              hipStream_t stream) {
  const float* p = (const float*)d_in[0];
  const float* t = (const float*)d_in[1];
  float* out = (float*)d_out;
  float* ws = (float*)d_ws;
  int n = in_sizes[0];  // 2,097,152 (divisible by 4096 waves)

  k_minmax<<<dim3(MM_BLOCKS), dim3(256), 0, stream>>>(p, t, n, ws);
  k_main<<<dim3(MAIN_BLOCKS), dim3(256), 0, stream>>>(p, t, n, ws);
  k_reduceA<<<dim3(RED_BLOCKS), dim3(1024), 0, stream>>>(ws);
  k_final<<<dim3(1), dim3(1024), 0, stream>>>(ws, out, n);
}

// Round 2
// 139.109 us; speedup vs baseline: 1.2210x; 1.2210x over previous
//
#include <hip/hip_runtime.h>
#include <math.h>

#ifndef __has_builtin
#define __has_builtin(x) 0
#endif
#if __has_builtin(__builtin_amdgcn_exp2f)
#define EXP2F(x) __builtin_amdgcn_exp2f(x)
#else
#define EXP2F(x) exp2f(x)
#endif
#if __has_builtin(__builtin_amdgcn_rcpf)
#define RCPF(x) __builtin_amdgcn_rcpf(x)
#else
#define RCPF(x) (1.0f / (x))
#endif

typedef _Float16 f16x8 __attribute__((ext_vector_type(8)));
typedef float f32x4 __attribute__((ext_vector_type(4)));

constexpr int KBINS = 32;
constexpr int MM_BLOCKS = 512;     // minmax stage-1 blocks
constexpr int MAIN_BLOCKS = 1024;  // main kernel blocks (4 waves each)
constexpr int WAVES_PER_BLOCK = 4;
constexpr int BATCH = 32;          // samples per wave-batch == MFMA K
constexpr int RED_BLOCKS = 64;
constexpr int PART_OFF_F = 4096;   // float offset of pab partials in ws
constexpr size_t REDA_OFF_B = (size_t)(PART_OFF_F + MAIN_BLOCKS * KBINS * KBINS) * 4;
// weights scaled by 2^9 before fp16 split (keeps Gaussian tails out of the
// fp16 flush-to-zero region); pab descaled by 2^18 in the fp64 epilogue.
constexpr float WSCALE = 512.0f;

#define MFMA16(a, b, c) __builtin_amdgcn_mfma_f32_16x16x32_f16((a), (b), (c), 0, 0, 0)

// sum over the 16-lane DPP row via rotate-accumulate (pure VALU, no DS pipe)
template <int CTRL>
__device__ __forceinline__ float rot_add(float v) {
  int r = __builtin_amdgcn_update_dpp(0, __builtin_bit_cast(int, v), CTRL, 0xF, 0xF, true);
  return v + __builtin_bit_cast(float, r);
}
__device__ __forceinline__ float row_sum16(float v) {
  v = rot_add<0x128>(v);  // row_ror:8
  v = rot_add<0x124>(v);  // row_ror:4
  v = rot_add<0x122>(v);  // row_ror:2
  v = rot_add<0x121>(v);  // row_ror:1
  return v;
}

// ---------------- Stage 0: global min/max over both arrays ----------------
__global__ __launch_bounds__(256) void k_minmax(const float* __restrict__ p,
                                                const float* __restrict__ t,
                                                int n, float* __restrict__ ws) {
  int tid = blockIdx.x * 256 + threadIdx.x;
  int nth = gridDim.x * 256;
  float mn = INFINITY, mx = -INFINITY;
  int n4 = n >> 2;
  const float4* p4 = (const float4*)p;
  const float4* t4 = (const float4*)t;
  for (int i = tid; i < n4; i += nth) {
    float4 a = p4[i];
    mn = fminf(mn, fminf(fminf(a.x, a.y), fminf(a.z, a.w)));
    mx = fmaxf(mx, fmaxf(fmaxf(a.x, a.y), fmaxf(a.z, a.w)));
    float4 b = t4[i];
    mn = fminf(mn, fminf(fminf(b.x, b.y), fminf(b.z, b.w)));
    mx = fmaxf(mx, fmaxf(fmaxf(b.x, b.y), fmaxf(b.z, b.w)));
  }
  for (int i = (n4 << 2) + tid; i < n; i += nth) {
    mn = fminf(mn, fminf(p[i], t[i]));
    mx = fmaxf(mx, fmaxf(p[i], t[i]));
  }
  for (int off = 32; off; off >>= 1) {
    mn = fminf(mn, __shfl_xor(mn, off, 64));
    mx = fmaxf(mx, __shfl_xor(mx, off, 64));
  }
  __shared__ float smn[4], smx[4];
  int wv = threadIdx.x >> 6;
  if ((threadIdx.x & 63) == 0) { smn[wv] = mn; smx[wv] = mx; }
  __syncthreads();
  if (threadIdx.x == 0) {
    mn = fminf(fminf(smn[0], smn[1]), fminf(smn[2], smn[3]));
    mx = fmaxf(fmaxf(smx[0], smx[1]), fmaxf(smx[2], smx[3]));
    ws[16 + 2 * blockIdx.x] = mn;
    ws[17 + 2 * blockIdx.x] = mx;
  }
}

// -------- Stage 1: fragment-direct Parzen weights + MFMA joint histogram --------
// Per wave: 32x32 pab as 4 16x16 MFMA accumulators. Lane (m=lane&15, quad=lane>>4)
// computes weights for bins {m, m+16} x samples {quad*8+j} -- exactly the
// mfma_f32_16x16x32 A/B fragment elements (A[m=lane&15][k=quad*8+j]).
// fp16 hi/lo split, 4 product terms -> exact to ~2^-24 relative.
__global__ __launch_bounds__(256, 4) void k_main(const float* __restrict__ p,
                                                 const float* __restrict__ t,
                                                 int n, float* __restrict__ ws) {
  __shared__ float s_par[4];
  __shared__ float red[WAVES_PER_BLOCK][KBINS * KBINS];  // 16 KB

  const int tidx = threadIdx.x;
  const int lane = tidx & 63;
  const int wv = tidx >> 6;

  // params from minmax partials (wave 0)
  if (tidx < 64) {
    float mn = INFINITY, mx = -INFINITY;
    for (int b = lane; b < MM_BLOCKS; b += 64) {
      mn = fminf(mn, ws[16 + 2 * b]);
      mx = fmaxf(mx, ws[17 + 2 * b]);
    }
    for (int off = 32; off; off >>= 1) {
      mn = fminf(mn, __shfl_xor(mn, off, 64));
      mx = fmaxf(mx, __shfl_xor(mx, off, 64));
    }
    if (lane == 0) {
      bool in_range = (mx <= 1.0f) && (mn >= 0.0f);
      float minv = in_range ? 0.0f : mn;
      float maxv = in_range ? 1.0f : mx;
      float drange = maxv - minv;
      float sigma = drange * (1.0f / (KBINS - 1));  // SIGMA_RATIO = 1
      float preterm = 1.0f / (2.0f * sigma * sigma);
      s_par[0] = minv;
      s_par[1] = drange * (1.0f / (KBINS - 1));              // bin spacing
      s_par[2] = preterm * 1.44269504088896340736f;          // preterm*log2(e)
    }
  }
  __syncthreads();
  const float minv = s_par[0], delta = s_par[1];
  const float npl2 = -s_par[2];

  const int m = lane & 15;
  const int quad = lane >> 4;
  const int qb = quad << 3;
  const float c0 = fmaf(delta, (float)m, minv);
  const float c1 = fmaf(delta, (float)(m + 16), minv);

  f32x4 acc00 = {0.f, 0.f, 0.f, 0.f};
  f32x4 acc01 = {0.f, 0.f, 0.f, 0.f};
  f32x4 acc10 = {0.f, 0.f, 0.f, 0.f};
  f32x4 acc11 = {0.f, 0.f, 0.f, 0.f};

  const int per_wave = n >> 12;  // n / 4096 waves = 512
  const int base = (blockIdx.x * WAVES_PER_BLOCK + wv) * per_wave;
  const int li = lane & 31;
  const float* __restrict__ src = (lane & 32) ? t : p;
  const int loff = (lane & 32) ? base - 32 : base;  // src[loff + it + lane-part]

  for (int it = 0; it < per_wave; it += BATCH) {
    // lanes 0-31: p[base+it+0..31]; lanes 32-63: t[base+it+0..31]
    float xv = src[loff + it + lane - (lane & 32) + (lane & 32 ? 32 : 0)];
    // (simplified): lanes hold src[base + it + li]
    xv = src[base + it + li];

    f16x8 Ah0, Al0, Ah1, Al1, Bh0, Bl0, Bh1, Bl1;
#pragma unroll
    for (int j = 0; j < 8; ++j) {
      float xa = __shfl(xv, qb + j, 64);       // pred sample quad*8+j
      float xb = __shfl(xv, 32 + qb + j, 64);  // target sample quad*8+j
      {  // A (pred) weights, bins m and m+16
        float d0 = xa - c0, d1 = xa - c1;
        float e0 = EXP2F((npl2 * d0) * d0);
        float e1 = EXP2F((npl2 * d1) * d1);
        float s = row_sum16(e0 + e1);
        float inv = RCPF(s);
        inv = inv * fmaf(-s, inv, 2.0f);  // Newton -> ~0.5 ulp
        inv *= WSCALE;
        float w0 = e0 * inv, w1 = e1 * inv;
        _Float16 h0 = (_Float16)w0;
        _Float16 l0 = (_Float16)(w0 - (float)h0);
        _Float16 h1 = (_Float16)w1;
        _Float16 l1 = (_Float16)(w1 - (float)h1);
        Ah0[j] = h0; Al0[j] = l0; Ah1[j] = h1; Al1[j] = l1;
      }
      {  // B (target) weights
        float d0 = xb - c0, d1 = xb - c1;
        float e0 = EXP2F((npl2 * d0) * d0);
        float e1 = EXP2F((npl2 * d1) * d1);
        float s = row_sum16(e0 + e1);
        float inv = RCPF(s);
        inv = inv * fmaf(-s, inv, 2.0f);
        inv *= WSCALE;
        float w0 = e0 * inv, w1 = e1 * inv;
        _Float16 h0 = (_Float16)w0;
        _Float16 l0 = (_Float16)(w0 - (float)h0);
        _Float16 h1 = (_Float16)w1;
        _Float16 l1 = (_Float16)(w1 - (float)h1);
        Bh0[j] = h0; Bl0[j] = l0; Bh1[j] = h1; Bl1[j] = l1;
      }
    }

    // 4 tiles x 4 split terms; K=32 = whole batch per MFMA
    acc00 = MFMA16(Ah0, Bh0, acc00);
    acc01 = MFMA16(Ah0, Bh1, acc01);
    acc10 = MFMA16(Ah1, Bh0, acc10);
    acc11 = MFMA16(Ah1, Bh1, acc11);
    acc00 = MFMA16(Al0, Bh0, acc00);
    acc01 = MFMA16(Al0, Bh1, acc01);
    acc10 = MFMA16(Al1, Bh0, acc10);
    acc11 = MFMA16(Al1, Bh1, acc11);
    acc00 = MFMA16(Ah0, Bl0, acc00);
    acc01 = MFMA16(Ah0, Bl1, acc01);
    acc10 = MFMA16(Ah1, Bl0, acc10);
    acc11 = MFMA16(Ah1, Bl1, acc11);
    acc00 = MFMA16(Al0, Bl0, acc00);
    acc01 = MFMA16(Al0, Bl1, acc01);
    acc10 = MFMA16(Al1, Bl0, acc10);
    acc11 = MFMA16(Al1, Bl1, acc11);
  }

  // epilogue: C/D layout col=lane&15, row=quad*4+reg -> per-wave 32x32 in LDS
#pragma unroll
  for (int reg = 0; reg < 4; ++reg) {
    int r0 = quad * 4 + reg;
    red[wv][r0 * KBINS + m] = acc00[reg];
    red[wv][r0 * KBINS + 16 + m] = acc01[reg];
    red[wv][(16 + r0) * KBINS + m] = acc10[reg];
    red[wv][(16 + r0) * KBINS + 16 + m] = acc11[reg];
  }
  __syncthreads();

  int cell = tidx * 4;
  float4 out4;
  out4.x = (red[0][cell + 0] + red[1][cell + 0]) + (red[2][cell + 0] + red[3][cell + 0]);
  out4.y = (red[0][cell + 1] + red[1][cell + 1]) + (red[2][cell + 1] + red[3][cell + 1]);
  out4.z = (red[0][cell + 2] + red[1][cell + 2]) + (red[2][cell + 2] + red[3][cell + 2]);
  out4.w = (red[0][cell + 3] + red[1][cell + 3]) + (red[2][cell + 3] + red[3][cell + 3]);
  float4* part = (float4*)(ws + PART_OFF_F + (size_t)blockIdx.x * 1024);
  part[tidx] = out4;
}

// ---------------- Stage 2a: reduce 1024 fp32 partials -> 64 fp64 partials ----------------
__global__ __launch_bounds__(1024) void k_reduceA(float* __restrict__ ws) {
  const float* part = ws + PART_OFF_F;
  double* outp = (double*)((char*)ws + REDA_OFF_B);
  int tid = threadIdx.x;
  int r = blockIdx.x;
  double s = 0.0;
#pragma unroll
  for (int b = 0; b < MAIN_BLOCKS / RED_BLOCKS; ++b)
    s += (double)part[(size_t)(r * (MAIN_BLOCKS / RED_BLOCKS) + b) * 1024 + tid];
  outp[(size_t)r * 1024 + tid] = s;
}

// ---------------- Stage 2b: final fp64 reduce + MI formula ----------------
__global__ __launch_bounds__(1024) void k_final(const float* __restrict__ ws_f,
                                                float* __restrict__ out, int n) {
  const double* parts = (const double*)((const char*)ws_f + REDA_OFF_B);
  __shared__ double pab_s[1024];
  __shared__ double pa_s[32], pb_s[32];
  __shared__ double wsum[16];
  int tid = threadIdx.x;
  double s = 0.0;
#pragma unroll 8
  for (int r = 0; r < RED_BLOCKS; ++r) s += parts[(size_t)r * 1024 + tid];
  // descale: weights carried a 2^9 factor each -> pab carries 2^18
  double pab = s / ((double)n * 262144.0);
  pab_s[tid] = pab;
  __syncthreads();
  if (tid < 32) {
    double a = 0.0;
    for (int l = 0; l < 32; ++l) a += pab_s[tid * 32 + l];
    pa_s[tid] = a;
  } else if (tid < 64) {
    int l = tid - 32;
    double b = 0.0;
    for (int k2 = 0; k2 < 32; ++k2) b += pab_s[k2 * 32 + l];
    pb_s[l] = b;
  }
  __syncthreads();
  int k = tid >> 5, l = tid & 31;
  double papb = pa_s[k] * pb_s[l];
  double v = pab * log((pab + 1e-7) / (papb + 1e-7) + 1e-7);
  for (int off = 32; off; off >>= 1) v += __shfl_down(v, off, 64);
  if ((tid & 63) == 0) wsum[tid >> 6] = v;
  __syncthreads();
  if (tid < 64) {
    double w = (tid < 16) ? wsum[tid] : 0.0;
    for (int off = 8; off; off >>= 1) w += __shfl_down(w, off, 64);
    if (tid == 0) out[0] = (float)(-w);
  }
}

extern "C" void kernel_launch(void* const* d_in, const int* in_sizes, int n_in,
                              void* d_out, int out_size, void* d_ws, size_t ws_size,
                              hipStream_t stream) {
  const float* p = (const float*)d_in[0];
  const float* t = (const float*)d_in[1];
  float* out = (float*)d_out;
  float* ws = (float*)d_ws;
  int n = in_sizes[0];  // 2,097,152

  k_minmax<<<dim3(MM_BLOCKS), dim3(256), 0, stream>>>(p, t, n, ws);
  k_main<<<dim3(MAIN_BLOCKS), dim3(256), 0, stream>>>(p, t, n, ws);
  k_reduceA<<<dim3(RED_BLOCKS), dim3(1024), 0, stream>>>(ws);
  k_final<<<dim3(1), dim3(1024), 0, stream>>>(ws, out, n);
}

// Round 4
// 130.232 us; speedup vs baseline: 1.3042x; 1.0682x over previous
//
#include <hip/hip_runtime.h>
#include <math.h>

#ifndef __has_builtin
#define __has_builtin(x) 0
#endif
#if __has_builtin(__builtin_amdgcn_exp2f)
#define EXP2F(x) __builtin_amdgcn_exp2f(x)
#else
#define EXP2F(x) exp2f(x)
#endif
#if __has_builtin(__builtin_amdgcn_rcpf)
#define RCPF(x) __builtin_amdgcn_rcpf(x)
#else
#define RCPF(x) (1.0f / (x))
#endif

typedef _Float16 f16x8 __attribute__((ext_vector_type(8)));
typedef _Float16 h2 __attribute__((ext_vector_type(2)));
typedef float f32x4 __attribute__((ext_vector_type(4)));

union Frag {
  f16x8 v;
  h2 p[4];
  _Float16 e[8];
};

__device__ __forceinline__ h2 pkrtz(float a, float b) {
#if __has_builtin(__builtin_amdgcn_cvt_pkrtz)
  return __builtin_bit_cast(h2, __builtin_amdgcn_cvt_pkrtz(a, b));
#else
  h2 r; r.x = (_Float16)a; r.y = (_Float16)b; return r;
#endif
}

constexpr int KBINS = 32;
constexpr int MM_BLOCKS = 512;     // minmax stage-1 blocks
constexpr int MAIN_BLOCKS = 1024;  // main kernel blocks
constexpr int NTHR = 512;          // 8 waves/block -> up to 32 waves/CU
constexpr int WPB = 8;
constexpr int BATCH = 32;          // samples per wave-batch == MFMA K
constexpr int RED_BLOCKS = 64;
constexpr int PART_OFF_F = 4096;   // float offset of pab partials in ws
constexpr size_t REDA_OFF_B = (size_t)(PART_OFF_F + MAIN_BLOCKS * KBINS * KBINS) * 4;
constexpr float WSCALE = 512.0f;   // 2^9, folded into exp arg (+9.0f)

#define MFMA16(a, b, c) __builtin_amdgcn_mfma_f32_16x16x32_f16((a), (b), (c), 0, 0, 0)

// 16-lane DPP row sum via rotate-accumulate (pure VALU, no DS pipe)
template <int CTRL>
__device__ __forceinline__ float rot_add(float v) {
  int r = __builtin_amdgcn_update_dpp(0, __builtin_bit_cast(int, v), CTRL, 0xF, 0xF, true);
  return v + __builtin_bit_cast(float, r);
}
__device__ __forceinline__ float row_sum16(float v) {
  v = rot_add<0x128>(v);  // row_ror:8
  v = rot_add<0x124>(v);  // row_ror:4
  v = rot_add<0x122>(v);  // row_ror:2
  v = rot_add<0x121>(v);  // row_ror:1
  return v;
}

// normalized Parzen weights (x 512) for bins m (w0) and m+16 (w1).
// exp arg carries +9 (2^9 scale); rcp+Newton ~0.5 ulp; x512 restores scale
// after normalizing by the scaled row sum.
__device__ __forceinline__ void wpair(float x, float c0, float c1, float npl2,
                                      float& w0, float& w1) {
  float d0 = x - c0, d1 = x - c1;
  float e0 = EXP2F(fmaf(npl2 * d0, d0, 9.0f));
  float e1 = EXP2F(fmaf(npl2 * d1, d1, 9.0f));
  float s = row_sum16(e0 + e1);
  float inv = RCPF(s);
  inv = inv * fmaf(-s, inv, 2.0f);
  inv *= WSCALE;
  w0 = e0 * inv;
  w1 = e1 * inv;
}

// ---------------- Stage 0: global min/max over both arrays ----------------
__global__ __launch_bounds__(256) void k_minmax(const float* __restrict__ p,
                                                const float* __restrict__ t,
                                                int n, float* __restrict__ ws) {
  int tid = blockIdx.x * 256 + threadIdx.x;
  int nth = gridDim.x * 256;
  float mn = INFINITY, mx = -INFINITY;
  int n4 = n >> 2;
  const float4* p4 = (const float4*)p;
  const float4* t4 = (const float4*)t;
  for (int i = tid; i < n4; i += nth) {
    float4 a = p4[i];
    mn = fminf(mn, fminf(fminf(a.x, a.y), fminf(a.z, a.w)));
    mx = fmaxf(mx, fmaxf(fmaxf(a.x, a.y), fmaxf(a.z, a.w)));
    float4 b = t4[i];
    mn = fminf(mn, fminf(fminf(b.x, b.y), fminf(b.z, b.w)));
    mx = fmaxf(mx, fmaxf(fmaxf(b.x, b.y), fmaxf(b.z, b.w)));
  }
  for (int i = (n4 << 2) + tid; i < n; i += nth) {
    mn = fminf(mn, fminf(p[i], t[i]));
    mx = fmaxf(mx, fmaxf(p[i], t[i]));
  }
  for (int off = 32; off; off >>= 1) {
    mn = fminf(mn, __shfl_xor(mn, off, 64));
    mx = fmaxf(mx, __shfl_xor(mx, off, 64));
  }
  __shared__ float smn[4], smx[4];
  int wv = threadIdx.x >> 6;
  if ((threadIdx.x & 63) == 0) { smn[wv] = mn; smx[wv] = mx; }
  __syncthreads();
  if (threadIdx.x == 0) {
    mn = fminf(fminf(smn[0], smn[1]), fminf(smn[2], smn[3]));
    mx = fmaxf(fmaxf(smx[0], smx[1]), fmaxf(smx[2], smx[3]));
    ws[16 + 2 * blockIdx.x] = mn;
    ws[17 + 2 * blockIdx.x] = mx;
  }
}

// -------- Stage 1: fragment-direct Parzen weights + MFMA joint histogram --------
// Lane (m=lane&15, quad=lane>>4) computes weights for bins {m, m+16} x samples
// {quad*8+j} -- exactly the mfma_f32_16x16x32_f16 A/B fragment elements.
// Sample values come from quad-uniform global float4 loads (L1 broadcast).
// fp16 hi/lo split, 4 product terms -> exact to ~2^-22 relative.
__global__ __launch_bounds__(NTHR, 4) void k_main(const float* __restrict__ p,
                                                  const float* __restrict__ t,
                                                  int n, float* __restrict__ ws) {
  __shared__ __align__(16) float red[WPB][KBINS * KBINS];  // 32 KB
  __shared__ float s_par[4];

  const int tidx = threadIdx.x;
  const int lane = tidx & 63;
  const int wv = tidx >> 6;

  // params from minmax partials (wave 0)
  if (tidx < 64) {
    float mn = INFINITY, mx = -INFINITY;
    for (int b = lane; b < MM_BLOCKS; b += 64) {
      mn = fminf(mn, ws[16 + 2 * b]);
      mx = fmaxf(mx, ws[17 + 2 * b]);
    }
    for (int off = 32; off; off >>= 1) {
      mn = fminf(mn, __shfl_xor(mn, off, 64));
      mx = fmaxf(mx, __shfl_xor(mx, off, 64));
    }
    if (lane == 0) {
      bool in_range = (mx <= 1.0f) && (mn >= 0.0f);
      float minv = in_range ? 0.0f : mn;
      float maxv = in_range ? 1.0f : mx;
      float drange = maxv - minv;
      float sigma = drange * (1.0f / (KBINS - 1));  // SIGMA_RATIO = 1
      float preterm = 1.0f / (2.0f * sigma * sigma);
      s_par[0] = minv;
      s_par[1] = drange * (1.0f / (KBINS - 1));     // bin spacing
      s_par[2] = preterm * 1.44269504088896340736f; // preterm * log2(e)
    }
  }
  __syncthreads();
  const float minv = s_par[0], delta = s_par[1];
  const float npl2 = -s_par[2];

  const int m = lane & 15;
  const int quad = lane >> 4;
  const int qb = quad << 3;
  const float c0 = fmaf(delta, (float)m, minv);
  const float c1 = fmaf(delta, (float)(m + 16), minv);

  f32x4 acc00 = {0.f, 0.f, 0.f, 0.f};
  f32x4 acc01 = {0.f, 0.f, 0.f, 0.f};
  f32x4 acc10 = {0.f, 0.f, 0.f, 0.f};
  f32x4 acc11 = {0.f, 0.f, 0.f, 0.f};

  const int per_wave = n >> 13;  // n / 8192 waves = 256
  const int base = (blockIdx.x * WPB + wv) * per_wave;

  for (int it = 0; it < per_wave; it += BATCH) {
    const int sbase = base + it + qb;  // quad-uniform, 32B-aligned
    // 16 lanes of each quad load the same 16B -> L1 broadcast, VMEM only
    float4 a0 = *(const float4*)(p + sbase);
    float4 a1 = *(const float4*)(p + sbase + 4);
    float4 b0 = *(const float4*)(t + sbase);
    float4 b1 = *(const float4*)(t + sbase + 4);
    float xa[8] = {a0.x, a0.y, a0.z, a0.w, a1.x, a1.y, a1.z, a1.w};
    float xb[8] = {b0.x, b0.y, b0.z, b0.w, b1.x, b1.y, b1.z, b1.w};

    Frag Ah0, Al0, Ah1, Al1, Bh0, Bl0, Bh1, Bl1;
#pragma unroll
    for (int jp = 0; jp < 4; ++jp) {
      {  // A (pred), samples 2jp, 2jp+1
        float w00, w10, w01, w11;
        wpair(xa[2 * jp], c0, c1, npl2, w00, w10);
        wpair(xa[2 * jp + 1], c0, c1, npl2, w01, w11);
        h2 h0 = pkrtz(w00, w01);
        h2 h1 = pkrtz(w10, w11);
        Ah0.p[jp] = h0;
        Ah1.p[jp] = h1;
        Al0.p[jp] = pkrtz(w00 - (float)h0.x, w01 - (float)h0.y);
        Al1.p[jp] = pkrtz(w10 - (float)h1.x, w11 - (float)h1.y);
      }
      {  // B (target)
        float w00, w10, w01, w11;
        wpair(xb[2 * jp], c0, c1, npl2, w00, w10);
        wpair(xb[2 * jp + 1], c0, c1, npl2, w01, w11);
        h2 h0 = pkrtz(w00, w01);
        h2 h1 = pkrtz(w10, w11);
        Bh0.p[jp] = h0;
        Bh1.p[jp] = h1;
        Bl0.p[jp] = pkrtz(w00 - (float)h0.x, w01 - (float)h0.y);
        Bl1.p[jp] = pkrtz(w10 - (float)h1.x, w11 - (float)h1.y);
      }
    }
    // 4 tiles x 4 split terms (hh, lh, hl, ll)
    acc00 = MFMA16(Ah0.v, Bh0.v, acc00);
    acc01 = MFMA16(Ah0.v, Bh1.v, acc01);
    acc10 = MFMA16(Ah1.v, Bh0.v, acc10);
    acc11 = MFMA16(Ah1.v, Bh1.v, acc11);
    acc00 = MFMA16(Al0.v, Bh0.v, acc00);
    acc01 = MFMA16(Al0.v, Bh1.v, acc01);
    acc10 = MFMA16(Al1.v, Bh0.v, acc10);
    acc11 = MFMA16(Al1.v, Bh1.v, acc11);
    acc00 = MFMA16(Ah0.v, Bl0.v, acc00);
    acc01 = MFMA16(Ah0.v, Bl1.v, acc01);
    acc10 = MFMA16(Ah1.v, Bl0.v, acc10);
    acc11 = MFMA16(Ah1.v, Bl1.v, acc11);
    acc00 = MFMA16(Al0.v, Bl0.v, acc00);
    acc01 = MFMA16(Al0.v, Bl1.v, acc01);
    acc10 = MFMA16(Al1.v, Bl0.v, acc10);
    acc11 = MFMA16(Al1.v, Bl1.v, acc11);
  }

  // per-block reduction of 8 wave accumulators; C/D layout col=lane&15, row=quad*4+reg
#pragma unroll
  for (int reg = 0; reg < 4; ++reg) {
    int r0 = quad * 4 + reg;
    red[wv][r0 * KBINS + m] = acc00[reg];
    red[wv][r0 * KBINS + 16 + m] = acc01[reg];
    red[wv][(16 + r0) * KBINS + m] = acc10[reg];
    red[wv][(16 + r0) * KBINS + 16 + m] = acc11[reg];
  }
  __syncthreads();
  {
    int c = 2 * tidx;
    float s0 = 0.f, s1 = 0.f;
#pragma unroll
    for (int w = 0; w < WPB; ++w) {
      float2 v = *(const float2*)&red[w][c];
      s0 += v.x;
      s1 += v.y;
    }
    *(float2*)(ws + PART_OFF_F + (size_t)blockIdx.x * 1024 + c) = make_float2(s0, s1);
  }
}

// ---------------- Stage 2a: reduce 1024 fp32 partials -> 64 fp64 partials ----------------
__global__ __launch_bounds__(1024) void k_reduceA(float* __restrict__ ws) {
  const float* part = ws + PART_OFF_F;
  double* outp = (double*)((char*)ws + REDA_OFF_B);
  int tid = threadIdx.x;
  int r = blockIdx.x;
  double s = 0.0;
#pragma unroll
  for (int b = 0; b < MAIN_BLOCKS / RED_BLOCKS; ++b)
    s += (double)part[(size_t)(r * (MAIN_BLOCKS / RED_BLOCKS) + b) * 1024 + tid];
  outp[(size_t)r * 1024 + tid] = s;
}

// ---------------- Stage 2b: final fp64 reduce + MI formula ----------------
__global__ __launch_bounds__(1024) void k_final(const float* __restrict__ ws_f,
                                                float* __restrict__ out, int n) {
  const double* parts = (const double*)((const char*)ws_f + REDA_OFF_B);
  __shared__ double pab_s[1024];
  __shared__ double pa_s[32], pb_s[32];
  __shared__ double wsum[16];
  int tid = threadIdx.x;
  double s = 0.0;
#pragma unroll 8
  for (int r = 0; r < RED_BLOCKS; ++r) s += parts[(size_t)r * 1024 + tid];
  // descale: weights carried a 2^9 factor each -> pab carries 2^18
  double pab = s / ((double)n * 262144.0);
  pab_s[tid] = pab;
  __syncthreads();
  if (tid < 32) {
    double a = 0.0;
    for (int l = 0; l < 32; ++l) a += pab_s[tid * 32 + l];
    pa_s[tid] = a;
  } else if (tid < 64) {
    int l = tid - 32;
    double b = 0.0;
    for (int k2 = 0; k2 < 32; ++k2) b += pab_s[k2 * 32 + l];
    pb_s[l] = b;
  }
  __syncthreads();
  int k = tid >> 5, l = tid & 31;
  double papb = pa_s[k] * pb_s[l];
  double v = pab * log((pab + 1e-7) / (papb + 1e-7) + 1e-7);
  for (int off = 32; off; off >>= 1) v += __shfl_down(v, off, 64);
  if ((tid & 63) == 0) wsum[tid >> 6] = v;
  __syncthreads();
  if (tid < 64) {
    double w = (tid < 16) ? wsum[tid] : 0.0;
    for (int off = 8; off; off >>= 1) w += __shfl_down(w, off, 64);
    if (tid == 0) out[0] = (float)(-w);
  }
}

extern "C" void kernel_launch(void* const* d_in, const int* in_sizes, int n_in,
                              void* d_out, int out_size, void* d_ws, size_t ws_size,
                              hipStream_t stream) {
  const float* p = (const float*)d_in[0];
  const float* t = (const float*)d_in[1];
  float* out = (float*)d_out;
  float* ws = (float*)d_ws;
  int n = in_sizes[0];  // 2,097,152

  k_minmax<<<dim3(MM_BLOCKS), dim3(256), 0, stream>>>(p, t, n, ws);
  k_main<<<dim3(MAIN_BLOCKS), dim3(NTHR), 0, stream>>>(p, t, n, ws);
  k_reduceA<<<dim3(RED_BLOCKS), dim3(1024), 0, stream>>>(ws);
  k_final<<<dim3(1), dim3(1024), 0, stream>>>(ws, out, n);
}

// Round 5
// 128.612 us; speedup vs baseline: 1.3206x; 1.0126x over previous
//
#include <hip/hip_runtime.h>
#include <math.h>

#ifndef __has_builtin
#define __has_builtin(x) 0
#endif
#if __has_builtin(__builtin_amdgcn_exp2f)
#define EXP2F(x) __builtin_amdgcn_exp2f(x)
#else
#define EXP2F(x) exp2f(x)
#endif
#if __has_builtin(__builtin_amdgcn_rcpf)
#define RCPF(x) __builtin_amdgcn_rcpf(x)
#else
#define RCPF(x) (1.0f / (x))
#endif

typedef _Float16 f16x8 __attribute__((ext_vector_type(8)));
typedef _Float16 h2 __attribute__((ext_vector_type(2)));
typedef float f32x4 __attribute__((ext_vector_type(4)));

union Frag {
  f16x8 v;
  h2 p[4];
  _Float16 e[8];
};

__device__ __forceinline__ h2 pkrtz(float a, float b) {
#if __has_builtin(__builtin_amdgcn_cvt_pkrtz)
  return __builtin_bit_cast(h2, __builtin_amdgcn_cvt_pkrtz(a, b));
#else
  h2 r; r.x = (_Float16)a; r.y = (_Float16)b; return r;
#endif
}

constexpr int KBINS = 32;
constexpr int MM_BLOCKS = 512;     // minmax stage-1 blocks
constexpr int MAIN_BLOCKS = 1024;  // main kernel blocks
constexpr int NTHR = 512;          // 8 waves/block -> up to 32 waves/CU
constexpr int WPB = 8;
constexpr int BATCH = 32;          // samples per wave-batch == MFMA K
constexpr int NSLOT = 8;           // atomic accumulator slots (contention split)
constexpr int ACC_OFF_F = 4096;    // float offset of fp64 accumulator (byte 16384)
// scale: A' = e_a * 4096 / (sa*sb), B' = 64 * e_b  ->  A'*B' = w_a*w_b * 2^18

#define MFMA16(a, b, c) __builtin_amdgcn_mfma_f32_16x16x32_f16((a), (b), (c), 0, 0, 0)

// 16-lane DPP row sum via rotate-accumulate (pure VALU, no DS pipe)
template <int CTRL>
__device__ __forceinline__ float rot_add(float v) {
  int r = __builtin_amdgcn_update_dpp(0, __builtin_bit_cast(int, v), CTRL, 0xF, 0xF, true);
  return v + __builtin_bit_cast(float, r);
}
__device__ __forceinline__ float row_sum16(float v) {
  v = rot_add<0x128>(v);  // row_ror:8
  v = rot_add<0x124>(v);  // row_ror:4
  v = rot_add<0x122>(v);  // row_ror:2
  v = rot_add<0x121>(v);  // row_ror:1
  return v;
}

// raw (unnormalized, unscaled) Parzen exps for bins m (e0) and m+16 (e1),
// plus the 32-bin row sum s. Round-2 exact arithmetic form.
__device__ __forceinline__ void eraw(float x, float c0, float c1, float npl2,
                                     float& e0, float& e1, float& s) {
  float d0 = x - c0, d1 = x - c1;
  e0 = EXP2F((npl2 * d0) * d0);
  e1 = EXP2F((npl2 * d1) * d1);
  s = row_sum16(e0 + e1);
}

// ---------------- Stage 0: global min/max + accumulator zeroing ----------------
__global__ __launch_bounds__(256) void k_minmax(const float* __restrict__ p,
                                                const float* __restrict__ t,
                                                int n, float* __restrict__ ws) {
  int tid = blockIdx.x * 256 + threadIdx.x;
  int nth = gridDim.x * 256;
  // zero the fp64 atomic accumulator (poisoned 0xAA before every launch)
  if (tid < NSLOT * 1024) ((double*)(ws + ACC_OFF_F))[tid] = 0.0;

  float mn = INFINITY, mx = -INFINITY;
  int n4 = n >> 2;
  const float4* p4 = (const float4*)p;
  const float4* t4 = (const float4*)t;
  for (int i = tid; i < n4; i += nth) {
    float4 a = p4[i];
    mn = fminf(mn, fminf(fminf(a.x, a.y), fminf(a.z, a.w)));
    mx = fmaxf(mx, fmaxf(fmaxf(a.x, a.y), fmaxf(a.z, a.w)));
    float4 b = t4[i];
    mn = fminf(mn, fminf(fminf(b.x, b.y), fminf(b.z, b.w)));
    mx = fmaxf(mx, fmaxf(fmaxf(b.x, b.y), fmaxf(b.z, b.w)));
  }
  for (int i = (n4 << 2) + tid; i < n; i += nth) {
    mn = fminf(mn, fminf(p[i], t[i]));
    mx = fmaxf(mx, fmaxf(p[i], t[i]));
  }
  for (int off = 32; off; off >>= 1) {
    mn = fminf(mn, __shfl_xor(mn, off, 64));
    mx = fmaxf(mx, __shfl_xor(mx, off, 64));
  }
  __shared__ float smn[4], smx[4];
  int wv = threadIdx.x >> 6;
  if ((threadIdx.x & 63) == 0) { smn[wv] = mn; smx[wv] = mx; }
  __syncthreads();
  if (threadIdx.x == 0) {
    mn = fminf(fminf(smn[0], smn[1]), fminf(smn[2], smn[3]));
    mx = fmaxf(fmaxf(smx[0], smx[1]), fmaxf(smx[2], smx[3]));
    ws[16 + 2 * blockIdx.x] = mn;
    ws[17 + 2 * blockIdx.x] = mx;
  }
}

// -------- Stage 1: fragment-direct Parzen weights + MFMA joint histogram --------
// Lane (m=lane&15, quad=lane>>4) computes weights for bins {m, m+16} x samples
// {quad*8+j} -- exactly the mfma_f32_16x16x32_f16 A/B fragment elements.
// Normalization folded entirely into the A side: one rcp per sample pair.
// fp16 hi/lo split (RTZ hi via pkrtz, exact fp32 residual, RTN lo) -> ~2^-23.
__global__ __launch_bounds__(NTHR, 4) void k_main(const float* __restrict__ p,
                                                  const float* __restrict__ t,
                                                  int n, float* __restrict__ ws) {
  __shared__ __align__(16) float red[WPB][KBINS * KBINS];  // 32 KB
  __shared__ float s_par[4];

  const int tidx = threadIdx.x;
  const int lane = tidx & 63;
  const int wv = tidx >> 6;

  // params from minmax partials (wave 0)
  if (tidx < 64) {
    float mn = INFINITY, mx = -INFINITY;
    for (int b = lane; b < MM_BLOCKS; b += 64) {
      mn = fminf(mn, ws[16 + 2 * b]);
      mx = fmaxf(mx, ws[17 + 2 * b]);
    }
    for (int off = 32; off; off >>= 1) {
      mn = fminf(mn, __shfl_xor(mn, off, 64));
      mx = fmaxf(mx, __shfl_xor(mx, off, 64));
    }
    if (lane == 0) {
      bool in_range = (mx <= 1.0f) && (mn >= 0.0f);
      float minv = in_range ? 0.0f : mn;
      float maxv = in_range ? 1.0f : mx;
      float drange = maxv - minv;
      float sigma = drange * (1.0f / (KBINS - 1));  // SIGMA_RATIO = 1
      float preterm = 1.0f / (2.0f * sigma * sigma);
      s_par[0] = minv;
      s_par[1] = drange * (1.0f / (KBINS - 1));     // bin spacing
      s_par[2] = preterm * 1.44269504088896340736f; // preterm * log2(e)
    }
  }
  __syncthreads();
  const float minv = s_par[0], delta = s_par[1];
  const float npl2 = -s_par[2];

  const int m = lane & 15;
  const int quad = lane >> 4;
  const int qb = quad << 3;
  const float c0 = fmaf(delta, (float)m, minv);
  const float c1 = fmaf(delta, (float)(m + 16), minv);

  f32x4 acc00 = {0.f, 0.f, 0.f, 0.f};
  f32x4 acc01 = {0.f, 0.f, 0.f, 0.f};
  f32x4 acc10 = {0.f, 0.f, 0.f, 0.f};
  f32x4 acc11 = {0.f, 0.f, 0.f, 0.f};

  const int per_wave = n >> 13;  // n / 8192 waves = 256
  const int base = (blockIdx.x * WPB + wv) * per_wave;

  for (int it = 0; it < per_wave; it += BATCH) {
    const int sbase = base + it + qb;  // quad-uniform, 32B-aligned
    // 16 lanes of each quad load the same 16B -> L1 broadcast, VMEM only
    float4 a0 = *(const float4*)(p + sbase);
    float4 a1 = *(const float4*)(p + sbase + 4);
    float4 b0 = *(const float4*)(t + sbase);
    float4 b1 = *(const float4*)(t + sbase + 4);
    float xa[8] = {a0.x, a0.y, a0.z, a0.w, a1.x, a1.y, a1.z, a1.w};
    float xb[8] = {b0.x, b0.y, b0.z, b0.w, b1.x, b1.y, b1.z, b1.w};

    Frag Ah0, Al0, Ah1, Al1, Bh0, Bl0, Bh1, Bl1;
#pragma unroll
    for (int jp = 0; jp < 4; ++jp) {
      // raw exps + row sums for 2 A samples and 2 B samples (same k indices)
      float ea00, ea01, sa0, ea10, ea11, sa1;
      float eb00, eb01, sb0, eb10, eb11, sb1;
      eraw(xa[2 * jp],     c0, c1, npl2, ea00, ea01, sa0);
      eraw(xa[2 * jp + 1], c0, c1, npl2, ea10, ea11, sa1);
      eraw(xb[2 * jp],     c0, c1, npl2, eb00, eb01, sb0);
      eraw(xb[2 * jp + 1], c0, c1, npl2, eb10, eb11, sb1);
      // one rcp per sample pair: A' = e_a * 4096/(sa*sb), B' = 64*e_b
      float pr0 = sa0 * sb0;
      float i0 = RCPF(pr0);
      i0 = i0 * fmaf(-pr0, i0, 2.0f);  // Newton -> ~0.5 ulp
      i0 *= 4096.0f;
      float pr1 = sa1 * sb1;
      float i1 = RCPF(pr1);
      i1 = i1 * fmaf(-pr1, i1, 2.0f);
      i1 *= 4096.0f;
      float wa00 = ea00 * i0, wa01 = ea01 * i0;   // sample 0, bins m / m+16
      float wa10 = ea10 * i1, wa11 = ea11 * i1;   // sample 1
      float wb00 = eb00 * 64.0f, wb01 = eb01 * 64.0f;
      float wb10 = eb10 * 64.0f, wb11 = eb11 * 64.0f;
      // hi: pkrtz (RTZ; absorbed by exact residual). lo: exact fp32 residual, RTN.
      h2 ha0 = pkrtz(wa00, wa10);   // bin m, samples 2jp, 2jp+1
      h2 ha1 = pkrtz(wa01, wa11);   // bin m+16
      h2 hb0 = pkrtz(wb00, wb10);
      h2 hb1 = pkrtz(wb01, wb11);
      Ah0.p[jp] = ha0; Ah1.p[jp] = ha1;
      Bh0.p[jp] = hb0; Bh1.p[jp] = hb1;
      Al0.e[2 * jp]     = (_Float16)(wa00 - (float)ha0.x);
      Al0.e[2 * jp + 1] = (_Float16)(wa10 - (float)ha0.y);
      Al1.e[2 * jp]     = (_Float16)(wa01 - (float)ha1.x);
      Al1.e[2 * jp + 1] = (_Float16)(wa11 - (float)ha1.y);
      Bl0.e[2 * jp]     = (_Float16)(wb00 - (float)hb0.x);
      Bl0.e[2 * jp + 1] = (_Float16)(wb10 - (float)hb0.y);
      Bl1.e[2 * jp]     = (_Float16)(wb01 - (float)hb1.x);
      Bl1.e[2 * jp + 1] = (_Float16)(wb11 - (float)hb1.y);
    }
    // 4 tiles x 4 split terms (hh, lh, hl, ll)
    acc00 = MFMA16(Ah0.v, Bh0.v, acc00);
    acc01 = MFMA16(Ah0.v, Bh1.v, acc01);
    acc10 = MFMA16(Ah1.v, Bh0.v, acc10);
    acc11 = MFMA16(Ah1.v, Bh1.v, acc11);
    acc00 = MFMA16(Al0.v, Bh0.v, acc00);
    acc01 = MFMA16(Al0.v, Bh1.v, acc01);
    acc10 = MFMA16(Al1.v, Bh0.v, acc10);
    acc11 = MFMA16(Al1.v, Bh1.v, acc11);
    acc00 = MFMA16(Ah0.v, Bl0.v, acc00);
    acc01 = MFMA16(Ah0.v, Bl1.v, acc01);
    acc10 = MFMA16(Ah1.v, Bl0.v, acc10);
    acc11 = MFMA16(Ah1.v, Bl1.v, acc11);
    acc00 = MFMA16(Al0.v, Bl0.v, acc00);
    acc01 = MFMA16(Al0.v, Bl1.v, acc01);
    acc10 = MFMA16(Al1.v, Bl0.v, acc10);
    acc11 = MFMA16(Al1.v, Bl1.v, acc11);
  }

  // per-block reduction of 8 wave accumulators; C/D layout col=lane&15, row=quad*4+reg
#pragma unroll
  for (int reg = 0; reg < 4; ++reg) {
    int r0 = quad * 4 + reg;
    red[wv][r0 * KBINS + m] = acc00[reg];
    red[wv][r0 * KBINS + 16 + m] = acc01[reg];
    red[wv][(16 + r0) * KBINS + m] = acc10[reg];
    red[wv][(16 + r0) * KBINS + 16 + m] = acc11[reg];
  }
  __syncthreads();
  {
    int c = 2 * tidx;
    float s0 = 0.f, s1 = 0.f;
#pragma unroll
    for (int w = 0; w < WPB; ++w) {
      float2 v = *(const float2*)&red[w][c];
      s0 += v.x;
      s1 += v.y;
    }
    // native fp64 atomics into slot (blockIdx & 7): 128 contenders/address
    double* acc = (double*)(ws + ACC_OFF_F) + (size_t)(blockIdx.x & (NSLOT - 1)) * 1024;
    unsafeAtomicAdd(&acc[c], (double)s0);
    unsafeAtomicAdd(&acc[c + 1], (double)s1);
  }
}

// ---------------- Stage 2: final fp64 reduce + MI formula ----------------
__global__ __launch_bounds__(1024) void k_final(const float* __restrict__ ws_f,
                                                float* __restrict__ out, int n) {
  const double* acc = (const double*)(ws_f + ACC_OFF_F);
  __shared__ double pab_s[1024];
  __shared__ double pa_s[32], pb_s[32];
  __shared__ double wsum[16];
  int tid = threadIdx.x;
  double s = 0.0;
#pragma unroll
  for (int slot = 0; slot < NSLOT; ++slot) s += acc[(size_t)slot * 1024 + tid];
  // descale: A'*B' carried 2^18
  double pab = s / ((double)n * 262144.0);
  pab_s[tid] = pab;
  __syncthreads();
  if (tid < 32) {
    double a = 0.0;
    for (int l = 0; l < 32; ++l) a += pab_s[tid * 32 + l];
    pa_s[tid] = a;
  } else if (tid < 64) {
    int l = tid - 32;
    double b = 0.0;
    for (int k2 = 0; k2 < 32; ++k2) b += pab_s[k2 * 32 + l];
    pb_s[l] = b;
  }
  __syncthreads();
  int k = tid >> 5, l = tid & 31;
  double papb = pa_s[k] * pb_s[l];
  double v = pab * log((pab + 1e-7) / (papb + 1e-7) + 1e-7);
  for (int off = 32; off; off >>= 1) v += __shfl_down(v, off, 64);
  if ((tid & 63) == 0) wsum[tid >> 6] = v;
  __syncthreads();
  if (tid < 64) {
    double w = (tid < 16) ? wsum[tid] : 0.0;
    for (int off = 8; off; off >>= 1) w += __shfl_down(w, off, 64);
    if (tid == 0) out[0] = (float)(-w);
  }
}

extern "C" void kernel_launch(void* const* d_in, const int* in_sizes, int n_in,
                              void* d_out, int out_size, void* d_ws, size_t ws_size,
                              hipStream_t stream) {
  const float* p = (const float*)d_in[0];
  const float* t = (const float*)d_in[1];
  float* out = (float*)d_out;
  float* ws = (float*)d_ws;
  int n = in_sizes[0];  // 2,097,152

  k_minmax<<<dim3(MM_BLOCKS), dim3(256), 0, stream>>>(p, t, n, ws);
  k_main<<<dim3(MAIN_BLOCKS), dim3(NTHR), 0, stream>>>(p, t, n, ws);
  k_final<<<dim3(1), dim3(1024), 0, stream>>>(ws, out, n);
}